// Round 1
// baseline (741.064 us; speedup 1.0000x reference)
//
#include <hip/hip_runtime.h>
#include <math.h>

#define N_NODES 50000
#define N_EDGES 800000
#define E2 (N_EDGES + N_NODES)   // with self loops
#define F_IN 512
#define HEADS 8
#define HID 32
#define HC 256                    // HEADS*HID
#define NCLASS 32
#define NEG_SLOPE 0.2f

// ---------------------------------------------------------------- CSR build
__global__ void count_deg(const int* __restrict__ ei, int* __restrict__ deg) {
    int e = blockIdx.x * blockDim.x + threadIdx.x;
    if (e >= E2) return;
    int dst = (e < N_EDGES) ? ei[N_EDGES + e] : (e - N_EDGES);
    atomicAdd(&deg[dst], 1);
}

__global__ void scan_kernel(const int* __restrict__ deg, int* __restrict__ rowstart) {
    __shared__ int smem[1024];
    __shared__ int running_s;
    int t = threadIdx.x;
    if (t == 0) running_s = 0;
    __syncthreads();
    for (int base = 0; base < N_NODES; base += 1024) {
        int i = base + t;
        int v = (i < N_NODES) ? deg[i] : 0;
        smem[t] = v;
        __syncthreads();
        int x = v;
        for (int off = 1; off < 1024; off <<= 1) {
            int y = (t >= off) ? smem[t - off] : 0;
            __syncthreads();
            x += y;
            smem[t] = x;
            __syncthreads();
        }
        int run = running_s;
        if (i < N_NODES) rowstart[i] = run + x - v;   // exclusive prefix
        int total = smem[1023];
        __syncthreads();
        if (t == 0) running_s = run + total;
        __syncthreads();
    }
    if (t == 0) rowstart[N_NODES] = running_s;
}

__global__ void fill_csr(const int* __restrict__ ei, const int* __restrict__ rowstart,
                         int* __restrict__ cursor, int* __restrict__ csr_src) {
    int e = blockIdx.x * blockDim.x + threadIdx.x;
    if (e >= E2) return;
    int src, dst;
    if (e < N_EDGES) { src = ei[e]; dst = ei[N_EDGES + e]; }
    else             { src = e - N_EDGES; dst = src; }
    int p = atomicAdd(&cursor[dst], 1);
    csr_src[rowstart[dst] + p] = src;
}

// ---------------------------------------------------------------- fp32 GEMM
// C[M,NOUT] = A[M,K] @ B[K,NOUT], row-major, blockDim = (BM/TM)*(BN/TN) = 256
template<int BM, int BN, int BK, int TM, int TN, int K, int NOUT>
__global__ void __launch_bounds__(256) gemm_kernel(const float* __restrict__ A,
                                                   const float* __restrict__ B,
                                                   float* __restrict__ C, int M) {
    __shared__ float As[BK][BM];
    __shared__ float Bs[BK][BN];
    const int tid = threadIdx.x;
    const int bm = blockIdx.x * BM;
    const int bn = blockIdx.y * BN;
    constexpr int TX = BN / TN;           // threads along N
    const int tx = tid % TX;
    const int ty = tid / TX;
    float acc[TM][TN] = {};
    constexpr int A4 = BM * BK / 4;       // float4 count for A tile
    constexpr int AR = BK / 4;            // float4 per A row
    constexpr int B4 = BK * BN / 4;
    constexpr int BR = BN / 4;

    for (int k0 = 0; k0 < K; k0 += BK) {
        for (int i = tid; i < A4; i += 256) {
            int row = i / AR;
            int kc  = (i % AR) * 4;
            float4 v = make_float4(0.f, 0.f, 0.f, 0.f);
            int grow = bm + row;
            if (grow < M) v = *(const float4*)(A + (size_t)grow * K + k0 + kc);
            As[kc + 0][row] = v.x; As[kc + 1][row] = v.y;
            As[kc + 2][row] = v.z; As[kc + 3][row] = v.w;
        }
        for (int i = tid; i < B4; i += 256) {
            int row = i / BR;
            int nc  = (i % BR) * 4;
            *(float4*)&Bs[row][nc] = *(const float4*)(B + (size_t)(k0 + row) * NOUT + bn + nc);
        }
        __syncthreads();
        #pragma unroll
        for (int k = 0; k < BK; ++k) {
            float af[TM], bf[TN];
            #pragma unroll
            for (int i = 0; i < TM; ++i) af[i] = As[k][ty * TM + i];
            #pragma unroll
            for (int j = 0; j < TN; ++j) bf[j] = Bs[k][tx * TN + j];
            #pragma unroll
            for (int i = 0; i < TM; ++i)
                #pragma unroll
                for (int j = 0; j < TN; ++j)
                    acc[i][j] += af[i] * bf[j];
        }
        __syncthreads();
    }
    #pragma unroll
    for (int i = 0; i < TM; ++i) {
        int grow = bm + ty * TM + i;
        if (grow >= M) continue;
        float* cp = C + (size_t)grow * NOUT + bn + tx * TN;
        if (TN == 4)      *(float4*)cp = make_float4(acc[i][0], acc[i][1], acc[i][2], acc[i][3]);
        else if (TN == 2) *(float2*)cp = make_float2(acc[i][0], acc[i][1]);
        else for (int j = 0; j < TN; ++j) cp[j] = acc[i][j];
    }
}

// ---------------------------------------------------------------- scores
__global__ void scores1_kernel(const float* __restrict__ h, const float* __restrict__ asrc,
                               const float* __restrict__ adst,
                               float* __restrict__ ssrc, float* __restrict__ sdst) {
    int gid = blockIdx.x * blockDim.x + threadIdx.x;
    int n = gid >> 3, hh = gid & 7;
    if (n >= N_NODES) return;
    const float* hp = h + (size_t)n * HC + hh * HID;
    const float* as = asrc + hh * HID;
    const float* ad = adst + hh * HID;
    float s1 = 0.f, s2 = 0.f;
    #pragma unroll
    for (int c = 0; c < HID; ++c) { float v = hp[c]; s1 += v * as[c]; s2 += v * ad[c]; }
    ssrc[n * HEADS + hh] = s1;
    sdst[n * HEADS + hh] = s2;
}

__global__ void scores2_kernel(const float* __restrict__ h2, const float* __restrict__ asrc,
                               const float* __restrict__ adst,
                               float* __restrict__ ssrc, float* __restrict__ sdst) {
    int n = blockIdx.x * blockDim.x + threadIdx.x;
    if (n >= N_NODES) return;
    float s1 = 0.f, s2 = 0.f;
    #pragma unroll
    for (int c = 0; c < NCLASS; ++c) {
        float v = h2[(size_t)n * NCLASS + c];
        s1 += v * asrc[c]; s2 += v * adst[c];
    }
    ssrc[n] = s1; sdst[n] = s2;
}

// ---------------------------------------------------------------- layer-1 aggregation
// one 256-thread block per node; thread t -> head t>>5, chan t&31
__global__ void __launch_bounds__(256) agg1_kernel(const float* __restrict__ h,
        const float* __restrict__ ssrc, const float* __restrict__ sdst,
        const int* __restrict__ rowstart, const int* __restrict__ csr_src,
        const float* __restrict__ bias, float* __restrict__ out) {
    const int n = blockIdx.x;
    const int beg = rowstart[n], end = rowstart[n + 1];
    const int t = threadIdx.x;
    const int hh = t >> 5, lane = t & 31, c = t & 31;

    __shared__ float sm[HEADS], sd_[HEADS], sdall[HEADS];
    __shared__ float wbuf[32][HEADS];
    __shared__ int   srcbuf[32];

    if (t < HEADS) sdall[t] = sdst[(size_t)n * HEADS + t];
    __syncthreads();
    const float sdst_n = sdall[hh];

    // phase 1: per-head online softmax (m, s)
    float m = -INFINITY, s = 0.f;
    for (int e = beg + lane; e < end; e += 32) {
        int src = csr_src[e];
        float sc = ssrc[(size_t)src * HEADS + hh] + sdst_n;
        sc = sc > 0.f ? sc : NEG_SLOPE * sc;
        float nm = fmaxf(m, sc);
        s = s * expf(m - nm) + expf(sc - nm);   // expf(-inf)=0 handles first iter
        m = nm;
    }
    // butterfly reduce across the 32 lanes of this head group
    #pragma unroll
    for (int off = 16; off > 0; off >>= 1) {
        float om = __shfl_xor(m, off);
        float os = __shfl_xor(s, off);
        float nm = fmaxf(m, om);
        float a = (m  == -INFINITY) ? 0.f : s  * expf(m  - nm);
        float b = (om == -INFINITY) ? 0.f : os * expf(om - nm);
        m = nm; s = a + b;
    }
    if (lane == 0) { sm[hh] = m; sd_[hh] = s; }
    __syncthreads();

    // phase 2: accumulate sum_e w_e * h[src_e, hh, c] in 32-edge LDS chunks
    float acc = 0.f;
    for (int cbeg = beg; cbeg < end; cbeg += 32) {
        int cnt = min(32, end - cbeg);
        int ei = t >> 3, eh = t & 7;
        if (ei < cnt) {
            int src = csr_src[cbeg + ei];
            if (eh == 0) srcbuf[ei] = src;
            float sc = ssrc[(size_t)src * HEADS + eh] + sdall[eh];
            sc = sc > 0.f ? sc : NEG_SLOPE * sc;
            wbuf[ei][eh] = expf(sc - sm[eh]);
        }
        __syncthreads();
        for (int i = 0; i < cnt; ++i) {
            int src = srcbuf[i];
            acc += wbuf[i][hh] * h[(size_t)src * HC + hh * HID + c];
        }
        __syncthreads();
    }
    float o = acc / (sd_[hh] + 1e-16f) + bias[t];
    o = o > 0.f ? o : expm1f(o);                 // ELU between layers
    out[(size_t)n * HC + t] = o;
}

// ---------------------------------------------------------------- layer-2 aggregation
// one wave (64 threads) per node; H=1, C=32
__global__ void __launch_bounds__(64) agg2_kernel(const float* __restrict__ h2,
        const float* __restrict__ ssrc, const float* __restrict__ sdst,
        const int* __restrict__ rowstart, const int* __restrict__ csr_src,
        const float* __restrict__ bias, float* __restrict__ out) {
    const int n = blockIdx.x;
    const int beg = rowstart[n], end = rowstart[n + 1];
    const int t = threadIdx.x;
    const float sdst_n = sdst[n];

    float m = -INFINITY, s = 0.f;
    for (int e = beg + t; e < end; e += 64) {
        float sc = ssrc[csr_src[e]] + sdst_n;
        sc = sc > 0.f ? sc : NEG_SLOPE * sc;
        float nm = fmaxf(m, sc);
        s = s * expf(m - nm) + expf(sc - nm);
        m = nm;
    }
    #pragma unroll
    for (int off = 32; off > 0; off >>= 1) {
        float om = __shfl_xor(m, off);
        float os = __shfl_xor(s, off);
        float nm = fmaxf(m, om);
        float a = (m  == -INFINITY) ? 0.f : s  * expf(m  - nm);
        float b = (om == -INFINITY) ? 0.f : os * expf(om - nm);
        m = nm; s = a + b;
    }
    const int c = t & 31, half = t >> 5;
    float acc = 0.f;
    for (int e = beg + half; e < end; e += 2) {
        int src = csr_src[e];
        float sc = ssrc[src] + sdst_n;
        sc = sc > 0.f ? sc : NEG_SLOPE * sc;
        acc += expf(sc - m) * h2[(size_t)src * NCLASS + c];
    }
    acc += __shfl_down(acc, 32);
    if (t < 32) out[(size_t)n * NCLASS + c] = acc / (s + 1e-16f) + bias[c] + 1e-6f;
}

// ---------------------------------------------------------------- launcher
extern "C" void kernel_launch(void* const* d_in, const int* in_sizes, int n_in,
                              void* d_out, int out_size, void* d_ws, size_t ws_size,
                              hipStream_t stream) {
    const float* x        = (const float*)d_in[0];
    const int*   ei       = (const int*)  d_in[1];
    const float* W1       = (const float*)d_in[2];
    const float* att_src1 = (const float*)d_in[3];
    const float* att_dst1 = (const float*)d_in[4];
    const float* b1       = (const float*)d_in[5];
    const float* W2       = (const float*)d_in[6];
    const float* att_src2 = (const float*)d_in[7];
    const float* att_dst2 = (const float*)d_in[8];
    const float* b2       = (const float*)d_in[9];
    float* out = (float*)d_out;

    // workspace layout
    float* ws    = (float*)d_ws;
    float* h1    = ws;                         // N*HC
    float* out1  = h1 + (size_t)N_NODES * HC;  // N*HC
    float* h2    = out1 + (size_t)N_NODES * HC;       // N*NCLASS
    float* ssrc1 = h2 + (size_t)N_NODES * NCLASS;     // N*HEADS
    float* sdst1 = ssrc1 + (size_t)N_NODES * HEADS;   // N*HEADS
    float* ssrc2 = sdst1 + (size_t)N_NODES * HEADS;   // N
    float* sdst2 = ssrc2 + N_NODES;                   // N
    int* rowstart = (int*)(sdst2 + N_NODES);          // N+1
    int* deg      = rowstart + N_NODES + 1;           // N
    int* cursor   = deg + N_NODES;                    // N
    int* csr_src  = cursor + N_NODES;                 // E2

    // CSR build (ws is re-poisoned every call)
    hipMemsetAsync(deg, 0, N_NODES * sizeof(int), stream);
    hipMemsetAsync(cursor, 0, N_NODES * sizeof(int), stream);
    int eb = (E2 + 255) / 256;
    count_deg<<<eb, 256, 0, stream>>>(ei, deg);
    scan_kernel<<<1, 1024, 0, stream>>>(deg, rowstart);
    fill_csr<<<eb, 256, 0, stream>>>(ei, rowstart, cursor, csr_src);

    // layer 1
    {
        dim3 grid((N_NODES + 63) / 64, HC / 64);
        gemm_kernel<64, 64, 16, 4, 4, F_IN, HC><<<grid, 256, 0, stream>>>(x, W1, h1, N_NODES);
    }
    scores1_kernel<<<(N_NODES * HEADS + 255) / 256, 256, 0, stream>>>(h1, att_src1, att_dst1, ssrc1, sdst1);
    agg1_kernel<<<N_NODES, 256, 0, stream>>>(h1, ssrc1, sdst1, rowstart, csr_src, b1, out1);

    // layer 2
    {
        dim3 grid((N_NODES + 63) / 64, NCLASS / 32);
        gemm_kernel<64, 32, 16, 4, 2, HC, NCLASS><<<grid, 256, 0, stream>>>(out1, W2, h2, N_NODES);
    }
    scores2_kernel<<<(N_NODES + 255) / 256, 256, 0, stream>>>(h2, att_src2, att_dst2, ssrc2, sdst2);
    agg2_kernel<<<N_NODES, 64, 0, stream>>>(h2, ssrc2, sdst2, rowstart, csr_src, b2, out);
}